// Round 3
// baseline (556.556 us; speedup 1.0000x reference)
//
#include <hip/hip_runtime.h>
#include <math.h>

#define N_BINS 15
#define C 50
#define ROWS 64                      // rows per tile
#define TILE_LOG 3200                // 64*50 floats
#define TILE_FLOATS 3264             // + 64 labels (as float-sized slots)
#define WPB 2                        // waves per block
#define BLOCK (WPB * 64)
#define GRID 768                     // 3 blocks/CU * 256 CU

// ws layout: uint cnt[15] | uint acc[15] | float conf[15]

__device__ __forceinline__ void load_lds16(const float* g, float* l) {
    // async global->LDS DMA, 16B/lane; LDS dest = wave-uniform base + lane*16
    __builtin_amdgcn_global_load_lds(
        (const __attribute__((address_space(1))) unsigned int*)g,
        (__attribute__((address_space(3))) unsigned int*)l, 16, 0, 0);
}

// 14 vm ops: 12 full-wave + 1 half-wave (logits) + 1 quarter-wave (labels)
__device__ __forceinline__ void stage_tile(const float* __restrict__ src,
                                           const int* __restrict__ lbl,
                                           float* __restrict__ dst, int lane) {
    #pragma unroll
    for (int j = 0; j < 12; ++j)
        load_lds16(src + (j * 64 + lane) * 4, dst + j * 256);
    if (lane < 32) load_lds16(src + (12 * 64 + lane) * 4, dst + 12 * 256);
    if (lane < 16) load_lds16((const float*)lbl + lane * 4, dst + TILE_LOG);
}

__global__ __launch_bounds__(BLOCK) void ece_accum(
    const float* __restrict__ logits,
    const int*   __restrict__ labels,
    unsigned int* __restrict__ ws_cnt,
    unsigned int* __restrict__ ws_acc,
    float*        __restrict__ ws_conf,
    int n_rows)
{
    __shared__ float tiles[WPB * 2 * TILE_FLOATS];   // 52224 B
    __shared__ unsigned int s_cnt[N_BINS];
    __shared__ unsigned int s_acc[N_BINS];
    __shared__ float        s_conf[N_BINS];

    const int tid = threadIdx.x;
    if (tid < N_BINS) { s_cnt[tid] = 0u; s_acc[tid] = 0u; s_conf[tid] = 0.0f; }
    __syncthreads();

    const int wave = tid >> 6;
    const int lane = tid & 63;
    float* __restrict__ buf0 = &tiles[(wave * 2 + 0) * TILE_FLOATS];
    float* __restrict__ buf1 = &tiles[(wave * 2 + 1) * TILE_FLOATS];

    const int n_tiles  = n_rows / ROWS;              // 32768
    const int gwave    = blockIdx.x * WPB + wave;
    const int n_gwaves = GRID * WPB;                 // 1536

    int t = gwave;
    int cur = 0;
    if (t < n_tiles)
        stage_tile(logits + (size_t)t * TILE_LOG, labels + t * ROWS, buf0, lane);

    for (; t < n_tiles; t += n_gwaves) {
        const int tn = t + n_gwaves;
        const bool has_next = tn < n_tiles;
        float* __restrict__ bufc = cur ? buf1 : buf0;
        float* __restrict__ bufn = cur ? buf0 : buf1;

        if (has_next) {
            stage_tile(logits + (size_t)tn * TILE_LOG, labels + tn * ROWS, bufn, lane);
            // wait only for tile t's 14 DMAs; tile t+1's 14 stay in flight
            asm volatile("s_waitcnt vmcnt(14)" ::: "memory");
        } else {
            asm volatile("s_waitcnt vmcnt(0)" ::: "memory");
        }

        // ---- compute tile t from bufc ----
        const float2* __restrict__ r2 = (const float2*)(bufc + lane * C);
        float vals[C];
        #pragma unroll
        for (int k = 0; k < C / 2; ++k) {
            float2 p = r2[k];
            vals[2 * k]     = p.x;
            vals[2 * k + 1] = p.y;
        }
        const int label = ((const int*)bufc)[TILE_LOG + lane];

        float vmax = vals[0];
        int   amax = 0;
        #pragma unroll
        for (int k = 1; k < C; ++k)
            if (vals[k] > vmax) { vmax = vals[k]; amax = k; }  // first max kept

        float sum = 0.0f;
        #pragma unroll
        for (int k = 0; k < C; ++k) sum += __expf(vals[k] - vmax);
        float conf = 1.0f / sum;                 // == max(softmax(row))

        int bin = (int)ceilf(conf * 15.0f) - 1;  // searchsorted(uppers, conf, left)
        bin = bin < 0 ? 0 : (bin > N_BINS - 1 ? N_BINS - 1 : bin);

        atomicAdd(&s_cnt[bin], 1u);
        if (amax == label) atomicAdd(&s_acc[bin], 1u);
        atomicAdd(&s_conf[bin], conf);

        cur ^= 1;
    }

    // leftover rows (n_rows % 64) — scalar path, block 0 only (0 for this shape)
    const int rem_start = n_tiles * ROWS;
    const int rem = n_rows - rem_start;
    if (blockIdx.x == 0 && tid < rem) {
        const float* __restrict__ r = logits + (size_t)(rem_start + tid) * C;
        float vmax = r[0];
        int   amax = 0;
        for (int k = 1; k < C; ++k) {
            float v = r[k];
            if (v > vmax) { vmax = v; amax = k; }
        }
        float sum = 0.0f;
        for (int k = 0; k < C; ++k) sum += __expf(r[k] - vmax);
        float conf = 1.0f / sum;
        int bin = (int)ceilf(conf * 15.0f) - 1;
        bin = bin < 0 ? 0 : (bin > N_BINS - 1 ? N_BINS - 1 : bin);
        atomicAdd(&s_cnt[bin], 1u);
        if (amax == labels[rem_start + tid]) atomicAdd(&s_acc[bin], 1u);
        atomicAdd(&s_conf[bin], conf);
    }

    __syncthreads();
    if (tid < N_BINS && s_cnt[tid] != 0u) {
        atomicAdd(&ws_cnt[tid],  s_cnt[tid]);
        atomicAdd(&ws_acc[tid],  s_acc[tid]);
        atomicAdd(&ws_conf[tid], s_conf[tid]);
    }
}

__global__ __launch_bounds__(64) void ece_final(
    const unsigned int* __restrict__ ws_cnt,
    const unsigned int* __restrict__ ws_acc,
    const float*        __restrict__ ws_conf,
    float* __restrict__ out, float inv_n)
{
    int i = threadIdx.x;
    float v = 0.0f;
    if (i < N_BINS) {
        float cnt      = (float)ws_cnt[i];      // exact (< 2^24)
        float prop     = cnt * inv_n;
        float denom    = fmaxf(cnt, 1.0f);
        float avg_acc  = (float)ws_acc[i] / denom;
        float avg_conf = ws_conf[i] / denom;
        float gap      = avg_conf - avg_acc;
        bool  nonempty = cnt > 0.0f;
        out[1 + i]  = nonempty ? gap * prop : 0.0f;   // bin_over_confidence
        out[16 + i] = prop;                            // prop_in_bin
        v = nonempty ? fabsf(gap) * prop : 0.0f;
    }
    v += __shfl_down(v, 8, 64);
    v += __shfl_down(v, 4, 64);
    v += __shfl_down(v, 2, 64);
    v += __shfl_down(v, 1, 64);
    if (i == 0) out[0] = v;                            // ece
}

extern "C" void kernel_launch(void* const* d_in, const int* in_sizes, int n_in,
                              void* d_out, int out_size, void* d_ws, size_t ws_size,
                              hipStream_t stream)
{
    const float* logits = (const float*)d_in[0];
    const int*   labels = (const int*)d_in[1];
    const int n_rows = in_sizes[1];

    unsigned int* ws_cnt  = (unsigned int*)d_ws;
    unsigned int* ws_acc  = ws_cnt + N_BINS;
    float*        ws_conf = (float*)(ws_acc + N_BINS);

    hipMemsetAsync(d_ws, 0, 3 * N_BINS * sizeof(float), stream);

    ece_accum<<<GRID, BLOCK, 0, stream>>>(logits, labels, ws_cnt, ws_acc, ws_conf, n_rows);
    ece_final<<<1, 64, 0, stream>>>(ws_cnt, ws_acc, ws_conf, (float*)d_out,
                                    1.0f / (float)n_rows);
}